// Round 3
// baseline (25729.892 us; speedup 1.0000x reference)
//
#include <hip/hip_runtime.h>
#include <cstdint>
#include <cstddef>

#define SEQ 256
#define BATCH 128
#define HID 1024
#define H3 3072
#define TCH 32                 // timesteps per chunk
#define NCH (SEQ/TCH)          // chunks per layer
#define CROWS (TCH*BATCH)      // 4096 rows per chunk GEMM

typedef __bf16 bf16x8 __attribute__((ext_vector_type(8)));
typedef float f32x4 __attribute__((ext_vector_type(4)));
typedef unsigned short ushort8 __attribute__((ext_vector_type(8)));

static __device__ __forceinline__ unsigned short f2bf(float f){
  unsigned int u = __float_as_uint(f);
  u += 0x7fffu + ((u >> 16) & 1u);
  return (unsigned short)(u >> 16);
}
static __device__ __forceinline__ float sigm(float x){
  return 1.0f / (1.0f + __expf(-x));
}
static __device__ __forceinline__ float tanh_(float x){
  x = fminf(15.0f, fmaxf(-15.0f, x));
  float e = __expf(2.0f * x);
  return (e - 1.0f) / (e + 1.0f);
}

// ---------------- prologue kernels ----------------

__global__ __launch_bounds__(256) void cvt_bf16(const float* __restrict__ in,
                                                unsigned short* __restrict__ out, int n4){
  int i = blockIdx.x * blockDim.x + threadIdx.x;
  int stride = gridDim.x * blockDim.x;
  for (; i < n4; i += stride){
    float4 v = reinterpret_cast<const float4*>(in)[i];
    ushort4 o = { f2bf(v.x), f2bf(v.y), f2bf(v.z), f2bf(v.w) };
    reinterpret_cast<ushort4*>(out)[i] = o;
  }
}

__global__ __launch_bounds__(256) void embed_gather(const int* __restrict__ src,
                                                    const float* __restrict__ embW,
                                                    unsigned short* __restrict__ x0){
  int bx = blockIdx.x;            // = s*BATCH + b
  int s = bx >> 7, b = bx & 127;
  int row = src[b * SEQ + s];
  float4 v = reinterpret_cast<const float4*>(embW + (size_t)row * HID)[threadIdx.x];
  ushort4 o = { f2bf(v.x), f2bf(v.y), f2bf(v.z), f2bf(v.w) };
  reinterpret_cast<ushort4*>(x0 + (size_t)bx * HID)[threadIdx.x] = o;
}

__global__ __launch_bounds__(256) void zero_u32(unsigned* __restrict__ p, int n){
  int i = blockIdx.x * blockDim.x + threadIdx.x;
  if (i < n) p[i] = 0u;
}

// ---------------- chunk GEMM: gi = A @ B^T (unchanged from R2) ----------------
#define BM 128
#define BN 128
#define BK 32
#define LDT 40

__global__ __launch_bounds__(256) void gemm_xw(
    const unsigned short* __restrict__ A,
    const unsigned short* __restrict__ B,
    float* __restrict__ C)
{
  __shared__ unsigned short As[2][BM][LDT];
  __shared__ unsigned short Bs[2][BN][LDT];
  int tid = threadIdx.x;
  int lane = tid & 63, wid = tid >> 6;
  int fr = lane & 15, kg = lane >> 4;
  int wr = wid >> 1, wc = wid & 1;
  int brow = blockIdx.x * BM;
  int bcol = blockIdx.y * BN;

  int r0 = tid >> 2;
  int r1 = 64 + (tid >> 2);
  int k8 = (tid & 3) * 8;

  const unsigned short* Ab = A + (size_t)brow * HID;
  const unsigned short* Bb = B + (size_t)bcol * HID;

  f32x4 acc[4][4] = {};
  ushort8 a0, a1, b0, b1;

  a0 = *(const ushort8*)(Ab + (size_t)r0 * HID + k8);
  a1 = *(const ushort8*)(Ab + (size_t)r1 * HID + k8);
  b0 = *(const ushort8*)(Bb + (size_t)r0 * HID + k8);
  b1 = *(const ushort8*)(Bb + (size_t)r1 * HID + k8);
  *(ushort8*)&As[0][r0][k8] = a0;
  *(ushort8*)&As[0][r1][k8] = a1;
  *(ushort8*)&Bs[0][r0][k8] = b0;
  *(ushort8*)&Bs[0][r1][k8] = b1;
  __syncthreads();

  for (int kt = 0; kt < HID / BK; ++kt){
    int cur = kt & 1;
    if (kt < HID / BK - 1){
      int ko = (kt + 1) * BK + k8;
      a0 = *(const ushort8*)(Ab + (size_t)r0 * HID + ko);
      a1 = *(const ushort8*)(Ab + (size_t)r1 * HID + ko);
      b0 = *(const ushort8*)(Bb + (size_t)r0 * HID + ko);
      b1 = *(const ushort8*)(Bb + (size_t)r1 * HID + ko);
    }
    bf16x8 af[4], bf[4];
    #pragma unroll
    for (int m = 0; m < 4; ++m)
      af[m] = *(const bf16x8*)&As[cur][wr*64 + m*16 + fr][kg*8];
    #pragma unroll
    for (int n = 0; n < 4; ++n)
      bf[n] = *(const bf16x8*)&Bs[cur][wc*64 + n*16 + fr][kg*8];
    #pragma unroll
    for (int m = 0; m < 4; ++m)
      #pragma unroll
      for (int n = 0; n < 4; ++n)
        acc[m][n] = __builtin_amdgcn_mfma_f32_16x16x32_bf16(af[m], bf[n], acc[m][n], 0,0,0);
    if (kt < HID / BK - 1){
      int nxt = cur ^ 1;
      *(ushort8*)&As[nxt][r0][k8] = a0;
      *(ushort8*)&As[nxt][r1][k8] = a1;
      *(ushort8*)&Bs[nxt][r0][k8] = b0;
      *(ushort8*)&Bs[nxt][r1][k8] = b1;
      __syncthreads();
    }
  }

  #pragma unroll
  for (int m = 0; m < 4; ++m){
    int row = brow + wr*64 + m*16 + kg*4;
    #pragma unroll
    for (int n = 0; n < 4; ++n){
      int col = bcol + wc*64 + n*16 + fr;
      float* cp = C + (size_t)row * H3 + col;
      #pragma unroll
      for (int q = 0; q < 4; ++q) cp[(size_t)q * H3] = acc[m][n][q];
    }
  }
}

// f32 rows -> bf16 rows
__global__ __launch_bounds__(256) void cvt_rows(const float* __restrict__ in,
                                                unsigned short* __restrict__ out, int n4){
  int i = blockIdx.x * blockDim.x + threadIdx.x;
  int stride = gridDim.x * blockDim.x;
  for (; i < n4; i += stride){
    float4 v = reinterpret_cast<const float4*>(in)[i];
    ushort4 o = { f2bf(v.x), f2bf(v.y), f2bf(v.z), f2bf(v.w) };
    reinterpret_cast<ushort4*>(out)[i] = o;
  }
}

// ---------------- persistent GRU chunk kernel ----------------
// grid = 256 WGs: blockIdx.x = rg*64 + ct;  rg in [0,4): 32 batch rows,
// ct in [0,64): 16 hidden cols (x 3 gates = 48 weight rows, LDS-resident).
// 4 waves K-split the 1024-dim dot (8 k-steps each), reduce via LDS into wave 0.
// Sync: per-rowgroup producer counters cnt[rg][s] (monotone, zeroed per call).
#define LDW 1032   // padded LDS leading dim (elems): 2-way bank aliasing = free

__global__ __launch_bounds__(256) void gru_persist(
    const unsigned short* __restrict__ Whh,   // layer [3072][1024] bf16
    const float* __restrict__ bih,            // layer [3072]
    const float* __restrict__ bhh,
    const float* __restrict__ gi,             // [TCH*128][3072] f32 chunk x-part
    float* __restrict__ out,                  // d_out ys base (f32 h history)
    unsigned short* __restrict__ hbA,         // bf16 h ping-pong
    unsigned short* __restrict__ hbB,
    float* __restrict__ state_out,            // layer state slot
    int t0,                                   // global t of chunk start
    unsigned* __restrict__ cnt)               // [4][TCH-1]
{
  __shared__ unsigned short Wlds[48 * LDW];   // 99 KB
  __shared__ f32x4 red[18][64];               // 18 KB partial-acc exchange

  int tid = threadIdx.x;
  int lane = tid & 63, wid = tid >> 6;
  int ct = blockIdx.x & 63, rg = blockIdx.x >> 6;
  int c0 = ct * 16, rowbase = rg * 32;
  int fr = lane & 15, kg = lane >> 4;

  // stage this WG's 48x1024 weight slice into LDS (once per launch)
  #pragma unroll
  for (int j = 0; j < 24; ++j){
    int cid = j * 256 + tid;                  // 0..6143 chunks of 8 elems
    int r = cid >> 7, k8 = (cid & 127) * 8;
    int grow = (r >> 4) * HID + c0 + (r & 15);
    *(ushort8*)&Wlds[r * LDW + k8] = *(const ushort8*)(Whh + (size_t)grow * HID + k8);
  }
  __syncthreads();

  int colc = c0 + fr;
  float br_ = bih[colc] + bhh[colc];
  float bz_ = bih[HID + colc] + bhh[HID + colc];
  float bi_ = bih[2*HID + colc];
  float bh_ = bhh[2*HID + colc];

  for (int s = 0; s < TCH; ++s){
    int t = t0 + s;
    if (s > 0){
      if (tid == 0){
        unsigned* p = cnt + rg * (TCH-1) + (s - 1);
        while (__hip_atomic_load(p, __ATOMIC_RELAXED, __HIP_MEMORY_SCOPE_AGENT) < 64u)
          __builtin_amdgcn_s_sleep(2);
      }
      __syncthreads();
      __threadfence();   // acquire: other WGs' h writes now visible
    }
    const unsigned short* hbin  = (t & 1) ? hbB : hbA;
    unsigned short*       hbout = (t & 1) ? hbA : hbB;

    f32x4 acc[2][3] = {};
    if (t > 0){
      const unsigned short* a0p = hbin + (size_t)(rowbase + fr) * HID + kg * 8;
      const unsigned short* a1p = a0p + 16 * HID;
      int kb = wid * 8 * 32;                  // this wave's k-slice (elems)
      #pragma unroll
      for (int j = 0; j < 8; ++j){
        int ko = kb + j * 32;
        bf16x8 a0 = *(const bf16x8*)(a0p + ko);
        bf16x8 a1 = *(const bf16x8*)(a1p + ko);
        bf16x8 b0 = *(const bf16x8*)&Wlds[(     fr) * LDW + ko + kg * 8];
        bf16x8 b1 = *(const bf16x8*)&Wlds[(16 + fr) * LDW + ko + kg * 8];
        bf16x8 b2 = *(const bf16x8*)&Wlds[(32 + fr) * LDW + ko + kg * 8];
        acc[0][0] = __builtin_amdgcn_mfma_f32_16x16x32_bf16(a0, b0, acc[0][0], 0,0,0);
        acc[0][1] = __builtin_amdgcn_mfma_f32_16x16x32_bf16(a0, b1, acc[0][1], 0,0,0);
        acc[0][2] = __builtin_amdgcn_mfma_f32_16x16x32_bf16(a0, b2, acc[0][2], 0,0,0);
        acc[1][0] = __builtin_amdgcn_mfma_f32_16x16x32_bf16(a1, b0, acc[1][0], 0,0,0);
        acc[1][1] = __builtin_amdgcn_mfma_f32_16x16x32_bf16(a1, b1, acc[1][1], 0,0,0);
        acc[1][2] = __builtin_amdgcn_mfma_f32_16x16x32_bf16(a1, b2, acc[1][2], 0,0,0);
      }
      if (wid > 0){
        #pragma unroll
        for (int rt = 0; rt < 2; ++rt)
          #pragma unroll
          for (int g = 0; g < 3; ++g)
            red[(wid-1)*6 + rt*3 + g][lane] = acc[rt][g];
      }
    }
    __syncthreads();

    if (wid == 0){
      if (t > 0){
        #pragma unroll
        for (int w = 0; w < 3; ++w)
          #pragma unroll
          for (int rt = 0; rt < 2; ++rt)
            #pragma unroll
            for (int g = 0; g < 3; ++g)
              acc[rt][g] += red[w*6 + rt*3 + g][lane];
      }
      #pragma unroll
      for (int rt = 0; rt < 2; ++rt){
        #pragma unroll
        for (int q = 0; q < 4; ++q){
          int row = rowbase + rt*16 + kg*4 + q;
          const float* gp = gi + (size_t)(s*BATCH + row) * H3;
          float gr = gp[colc], gz = gp[HID + colc], gn = gp[2*HID + colc];
          float hold = (t > 0) ? out[((size_t)(t-1)*BATCH + row) * HID + colc] : 0.0f;
          float rg_ = sigm(gr + acc[rt][0][q] + br_);
          float zg  = sigm(gz + acc[rt][1][q] + bz_);
          float ng  = tanh_(gn + bi_ + rg_ * (acc[rt][2][q] + bh_));
          float hv  = (1.0f - zg) * ng + zg * hold;
          out[((size_t)t*BATCH + row) * HID + colc] = hv;
          hbout[(size_t)row * HID + colc] = f2bf(hv);
          if (t == SEQ-1) state_out[(size_t)row * HID + colc] = hv;
        }
      }
    }
    __threadfence();   // release my h writes before arrive
    __syncthreads();
    if (tid == 0 && s < TCH-1)
      __hip_atomic_fetch_add(cnt + rg*(TCH-1) + s, 1u,
                             __ATOMIC_RELEASE, __HIP_MEMORY_SCOPE_AGENT);
  }
}

// ---------------- launch ----------------

extern "C" void kernel_launch(void* const* d_in, const int* in_sizes, int n_in,
                              void* d_out, int out_size, void* d_ws, size_t ws_size,
                              hipStream_t stream){
  (void)in_sizes; (void)n_in; (void)out_size; (void)ws_size;
  const int*   src  = (const int*)  d_in[0];
  const float* embW = (const float*)d_in[1];
  const float* Wih  = (const float*)d_in[2];
  const float* Whh  = (const float*)d_in[3];
  const float* bih  = (const float*)d_in[4];
  const float* bhh  = (const float*)d_in[5];
  float* out = (float*)d_out;

  char* ws = (char*)d_ws;
  size_t off = 0;
  auto carve = [&](size_t bytes) -> void* {
    void* p = ws + off;
    off += (bytes + 255) & ~(size_t)255;
    return p;
  };
  const size_t WELEM = (size_t)2 * H3 * HID;
  unsigned short* wihb = (unsigned short*)carve(WELEM * 2);
  unsigned short* whhb = (unsigned short*)carve(WELEM * 2);
  unsigned short* x0   = (unsigned short*)carve((size_t)SEQ*BATCH*HID*2);
  float*          gi   = (float*)         carve((size_t)CROWS*H3*4);
  unsigned short* ybc  = (unsigned short*)carve((size_t)CROWS*HID*2);
  unsigned short* hbA  = (unsigned short*)carve((size_t)BATCH*HID*2);
  unsigned short* hbB  = (unsigned short*)carve((size_t)BATCH*HID*2);
  unsigned*       cnt  = (unsigned*)      carve((size_t)16 * 4 * (TCH-1) * 4);

  cvt_bf16<<<2048, 256, 0, stream>>>(Wih, wihb, (int)(WELEM/4));
  cvt_bf16<<<2048, 256, 0, stream>>>(Whh, whhb, (int)(WELEM/4));
  embed_gather<<<SEQ*BATCH, 256, 0, stream>>>(src, embW, x0);
  zero_u32<<<8, 256, 0, stream>>>(cnt, 16 * 4 * (TCH-1));

  float* state = out + (size_t)SEQ*BATCH*HID;
  for (int l = 0; l < 2; ++l){
    const float* bihl = bih + l*H3;
    const float* bhhl = bhh + l*H3;
    const unsigned short* wl = wihb + (size_t)l*H3*HID;
    const unsigned short* vl = whhb + (size_t)l*H3*HID;
    for (int cch = 0; cch < NCH; ++cch){
      const unsigned short* Achunk;
      if (l == 0){
        Achunk = x0 + (size_t)cch*CROWS*HID;
      } else {
        cvt_rows<<<2048, 256, 0, stream>>>(out + (size_t)cch*CROWS*HID, ybc,
                                           (int)((size_t)CROWS*HID/4));
        Achunk = ybc;
      }
      gemm_xw<<<dim3(CROWS/BM, H3/BN), 256, 0, stream>>>(Achunk, wl, gi);
      int launch_id = l*NCH + cch;
      gru_persist<<<256, 256, 0, stream>>>(
          vl, bihl, bhhl, gi, out, hbA, hbB,
          state + (size_t)l*BATCH*HID,
          cch*TCH,
          cnt + (size_t)launch_id * 4 * (TCH-1));
    }
  }
}

// Round 4
// 3769.386 us; speedup vs baseline: 6.8260x; 6.8260x over previous
//
#include <hip/hip_runtime.h>
#include <cstdint>
#include <cstddef>

#define SEQ 256
#define BATCH 128
#define HID 1024
#define H3 3072
#define TCH 32                 // timesteps per chunk
#define NCH (SEQ/TCH)          // chunks per layer
#define CROWS (TCH*BATCH)      // 4096 rows per chunk GEMM

typedef __bf16 bf16x8 __attribute__((ext_vector_type(8)));
typedef float f32x4 __attribute__((ext_vector_type(4)));
typedef unsigned short ushort8 __attribute__((ext_vector_type(8)));
typedef unsigned long long u64x2 __attribute__((ext_vector_type(2)));

static __device__ __forceinline__ unsigned short f2bf(float f){
  unsigned int u = __float_as_uint(f);
  u += 0x7fffu + ((u >> 16) & 1u);
  return (unsigned short)(u >> 16);
}
static __device__ __forceinline__ float sigm(float x){
  return 1.0f / (1.0f + __expf(-x));
}
static __device__ __forceinline__ float tanh_(float x){
  x = fminf(15.0f, fmaxf(-15.0f, x));
  float e = __expf(2.0f * x);
  return (e - 1.0f) / (e + 1.0f);
}

// ---------------- prologue kernels ----------------

__global__ __launch_bounds__(256) void cvt_bf16(const float* __restrict__ in,
                                                unsigned short* __restrict__ out, int n4){
  int i = blockIdx.x * blockDim.x + threadIdx.x;
  int stride = gridDim.x * blockDim.x;
  for (; i < n4; i += stride){
    float4 v = reinterpret_cast<const float4*>(in)[i];
    ushort4 o = { f2bf(v.x), f2bf(v.y), f2bf(v.z), f2bf(v.w) };
    reinterpret_cast<ushort4*>(out)[i] = o;
  }
}

__global__ __launch_bounds__(256) void embed_gather(const int* __restrict__ src,
                                                    const float* __restrict__ embW,
                                                    unsigned short* __restrict__ x0){
  int bx = blockIdx.x;            // = s*BATCH + b
  int s = bx >> 7, b = bx & 127;
  int row = src[b * SEQ + s];
  float4 v = reinterpret_cast<const float4*>(embW + (size_t)row * HID)[threadIdx.x];
  ushort4 o = { f2bf(v.x), f2bf(v.y), f2bf(v.z), f2bf(v.w) };
  reinterpret_cast<ushort4*>(x0 + (size_t)bx * HID)[threadIdx.x] = o;
}

__global__ __launch_bounds__(256) void zero_u32(unsigned* __restrict__ p, int n){
  int i = blockIdx.x * blockDim.x + threadIdx.x;
  if (i < n) p[i] = 0u;
}

// ---------------- chunk GEMM: gi = A @ B^T, C stored COLUMN-major ----------------
// A [CROWS][1024] bf16 row-major, B [3072][1024] bf16 row-major,
// C[col*CROWS + row] f32.  128x128 tile, BK=32, double-buffered LDS.
#define BM 128
#define BN 128
#define BK 32
#define LDT 40

__global__ __launch_bounds__(256) void gemm_xw(
    const unsigned short* __restrict__ A,
    const unsigned short* __restrict__ B,
    float* __restrict__ C)
{
  __shared__ unsigned short As[2][BM][LDT];
  __shared__ unsigned short Bs[2][BN][LDT];
  int tid = threadIdx.x;
  int lane = tid & 63, wid = tid >> 6;
  int fr = lane & 15, kg = lane >> 4;
  int wr = wid >> 1, wc = wid & 1;
  int brow = blockIdx.x * BM;
  int bcol = blockIdx.y * BN;

  int r0 = tid >> 2;
  int r1 = 64 + (tid >> 2);
  int k8 = (tid & 3) * 8;

  const unsigned short* Ab = A + (size_t)brow * HID;
  const unsigned short* Bb = B + (size_t)bcol * HID;

  f32x4 acc[4][4] = {};
  ushort8 a0, a1, b0, b1;

  a0 = *(const ushort8*)(Ab + (size_t)r0 * HID + k8);
  a1 = *(const ushort8*)(Ab + (size_t)r1 * HID + k8);
  b0 = *(const ushort8*)(Bb + (size_t)r0 * HID + k8);
  b1 = *(const ushort8*)(Bb + (size_t)r1 * HID + k8);
  *(ushort8*)&As[0][r0][k8] = a0;
  *(ushort8*)&As[0][r1][k8] = a1;
  *(ushort8*)&Bs[0][r0][k8] = b0;
  *(ushort8*)&Bs[0][r1][k8] = b1;
  __syncthreads();

  for (int kt = 0; kt < HID / BK; ++kt){
    int cur = kt & 1;
    if (kt < HID / BK - 1){
      int ko = (kt + 1) * BK + k8;
      a0 = *(const ushort8*)(Ab + (size_t)r0 * HID + ko);
      a1 = *(const ushort8*)(Ab + (size_t)r1 * HID + ko);
      b0 = *(const ushort8*)(Bb + (size_t)r0 * HID + ko);
      b1 = *(const ushort8*)(Bb + (size_t)r1 * HID + ko);
    }
    bf16x8 af[4], bfr[4];
    #pragma unroll
    for (int m = 0; m < 4; ++m)
      af[m] = *(const bf16x8*)&As[cur][wr*64 + m*16 + fr][kg*8];
    #pragma unroll
    for (int n = 0; n < 4; ++n)
      bfr[n] = *(const bf16x8*)&Bs[cur][wc*64 + n*16 + fr][kg*8];
    #pragma unroll
    for (int m = 0; m < 4; ++m)
      #pragma unroll
      for (int n = 0; n < 4; ++n)
        acc[m][n] = __builtin_amdgcn_mfma_f32_16x16x32_bf16(af[m], bfr[n], acc[m][n], 0,0,0);
    if (kt < HID / BK - 1){
      int nxt = cur ^ 1;
      *(ushort8*)&As[nxt][r0][k8] = a0;
      *(ushort8*)&As[nxt][r1][k8] = a1;
      *(ushort8*)&Bs[nxt][r0][k8] = b0;
      *(ushort8*)&Bs[nxt][r1][k8] = b1;
      __syncthreads();
    }
  }

  // column-major C write: rows contiguous -> one f32x4 per (m,n)
  #pragma unroll
  for (int m = 0; m < 4; ++m){
    int rowb = brow + wr*64 + m*16 + kg*4;
    #pragma unroll
    for (int n = 0; n < 4; ++n){
      int col = bcol + wc*64 + n*16 + fr;
      *(f32x4*)(C + (size_t)col * CROWS + rowb) = acc[m][n];
    }
  }
}

// ---------------- persistent GRU chunk kernel (fence-free LLC sync) ----------------
// grid 256 WGs: blockIdx.x = rg*64 + ct. rg: 32 batch rows; ct: 16 hidden cols
// (x3 gates = 48 weight rows LDS-resident). 4 waves K-split the 1024-dot.
// h exchanged as relaxed agent-scope u64 atomics (LLC-coherent, no fences).
#define LDW 1032

__global__ __launch_bounds__(256) void gru_persist(
    const unsigned short* __restrict__ Whh,   // layer [3072][1024] bf16
    const float* __restrict__ bih,
    const float* __restrict__ bhh,
    const float* __restrict__ gi,             // [3072][CROWS] col-major chunk
    float* __restrict__ ys_out,               // layer1: d_out ys base; else null
    unsigned short* __restrict__ x_next,      // layer0: x1 chunk base; else null
    unsigned long long* __restrict__ hbA,     // bf16 h ping-pong (u64 granules)
    unsigned long long* __restrict__ hbB,
    float* __restrict__ hf32,                 // f32 h carry across chunk launches
    float* __restrict__ state_out,            // layer state slot
    int t0,
    unsigned* __restrict__ cnt)               // [4][TCH] this launch's flags
{
  __shared__ unsigned short Wlds[48 * LDW];   // 99 KB
  __shared__ f32x4 red[4][2][3][64];          // 24.5 KB
  __shared__ unsigned short hvt[32][16];      // 1 KB

  int tid = threadIdx.x;
  int lane = tid & 63, wid = tid >> 6;
  int ct = blockIdx.x & 63, rg = blockIdx.x >> 6;
  int c0 = ct * 16, rowbase = rg * 32;
  int fr = lane & 15, kg = lane >> 4;

  // stage 48x1024 weight slice once per launch
  #pragma unroll
  for (int j = 0; j < 24; ++j){
    int cid = j * 256 + tid;
    int r = cid >> 7, k8 = (cid & 127) * 8;
    int grow = (r >> 4) * HID + c0 + (r & 15);
    *(ushort8*)&Wlds[r * LDW + k8] = *(const ushort8*)(Whh + (size_t)grow * HID + k8);
  }

  // epilogue cell assignment (2 adjacent-col cells per thread), loop-invariant
  int crow = tid >> 3;              // 0..31
  int ccol = (tid << 1) & 15;       // even col in [0,16)
  int rt_ = crow >> 4, r16 = crow & 15, kq = r16 >> 2, qq = r16 & 3;
  int l0 = kq * 16 + ccol, l1 = l0 + 1;
  int colc0 = c0 + ccol, colc1 = colc0 + 1;
  int growL = rowbase + crow;       // global batch row of my cells

  float br0 = bih[colc0] + bhh[colc0];
  float bz0 = bih[HID + colc0] + bhh[HID + colc0];
  float bi0 = bih[2*HID + colc0];
  float bh0 = bhh[2*HID + colc0];
  float br1 = bih[colc1] + bhh[colc1];
  float bz1 = bih[HID + colc1] + bhh[HID + colc1];
  float bi1 = bih[2*HID + colc1];
  float bh1 = bhh[2*HID + colc1];

  float hprev0 = 0.0f, hprev1 = 0.0f;
  if (t0 > 0){
    hprev0 = hf32[(size_t)growL * HID + colc0];
    hprev1 = hf32[(size_t)growL * HID + colc1];
  }
  __syncthreads();

  for (int s = 0; s < TCH; ++s){
    int t = t0 + s;
    // gi prefetch (independent of h) — issue before the poll
    size_t gro = (size_t)s * BATCH + growL;
    float gr0 = gi[(size_t)(0*HID + colc0) * CROWS + gro];
    float gz0 = gi[(size_t)(1*HID + colc0) * CROWS + gro];
    float gn0 = gi[(size_t)(2*HID + colc0) * CROWS + gro];
    float gr1 = gi[(size_t)(0*HID + colc1) * CROWS + gro];
    float gz1 = gi[(size_t)(1*HID + colc1) * CROWS + gro];
    float gn1 = gi[(size_t)(2*HID + colc1) * CROWS + gro];

    if (s > 0){
      if (tid == 0){
        unsigned* p = cnt + rg * TCH + (s - 1);
        int lim = 4000000;
        while (__hip_atomic_load(p, __ATOMIC_RELAXED, __HIP_MEMORY_SCOPE_AGENT) < 64u
               && --lim)
          __builtin_amdgcn_s_sleep(1);
      }
      __syncthreads();
      asm volatile("" ::: "memory");
    }
    const unsigned long long* hin = (t & 1) ? hbB : hbA;
    unsigned long long*       hout = (t & 1) ? hbA : hbB;

    f32x4 acc[2][3] = {};
    if (t > 0){
      const int wk0 = wid << 8;                 // wave k-slice base (elems)
      bf16x8 a[2][8];
      #pragma unroll
      for (int rt = 0; rt < 2; ++rt){
        size_t rb = (size_t)(rowbase + rt*16 + fr) * HID + wk0 + kg*8;
        #pragma unroll
        for (int j = 0; j < 8; ++j){
          size_t ui = (rb + (size_t)j*32) >> 2;
          unsigned long long u0 = __hip_atomic_load(hin + ui,     __ATOMIC_RELAXED, __HIP_MEMORY_SCOPE_AGENT);
          unsigned long long u1 = __hip_atomic_load(hin + ui + 1, __ATOMIC_RELAXED, __HIP_MEMORY_SCOPE_AGENT);
          u64x2 uu; uu[0] = u0; uu[1] = u1;
          a[rt][j] = __builtin_bit_cast(bf16x8, uu);
        }
      }
      #pragma unroll
      for (int j = 0; j < 8; ++j){
        int bo = wk0 + j*32 + kg*8;
        bf16x8 b0 = *(const bf16x8*)&Wlds[(     fr) * LDW + bo];
        bf16x8 b1 = *(const bf16x8*)&Wlds[(16 + fr) * LDW + bo];
        bf16x8 b2 = *(const bf16x8*)&Wlds[(32 + fr) * LDW + bo];
        acc[0][0] = __builtin_amdgcn_mfma_f32_16x16x32_bf16(a[0][j], b0, acc[0][0], 0,0,0);
        acc[0][1] = __builtin_amdgcn_mfma_f32_16x16x32_bf16(a[0][j], b1, acc[0][1], 0,0,0);
        acc[0][2] = __builtin_amdgcn_mfma_f32_16x16x32_bf16(a[0][j], b2, acc[0][2], 0,0,0);
        acc[1][0] = __builtin_amdgcn_mfma_f32_16x16x32_bf16(a[1][j], b0, acc[1][0], 0,0,0);
        acc[1][1] = __builtin_amdgcn_mfma_f32_16x16x32_bf16(a[1][j], b1, acc[1][1], 0,0,0);
        acc[1][2] = __builtin_amdgcn_mfma_f32_16x16x32_bf16(a[1][j], b2, acc[1][2], 0,0,0);
      }
    }

    // parallel reduction: all waves publish partials
    #pragma unroll
    for (int rt = 0; rt < 2; ++rt)
      #pragma unroll
      for (int g = 0; g < 3; ++g)
        red[wid][rt][g][lane] = acc[rt][g];
    __syncthreads();

    float v0[3], v1[3];
    #pragma unroll
    for (int g = 0; g < 3; ++g){
      float s0 = 0.f, s1 = 0.f;
      #pragma unroll
      for (int w = 0; w < 4; ++w){
        s0 += red[w][rt_][g][l0][qq];
        s1 += red[w][rt_][g][l1][qq];
      }
      v0[g] = s0; v1[g] = s1;
    }

    float rA = sigm(gr0 + v0[0] + br0);
    float zA = sigm(gz0 + v0[1] + bz0);
    float nA = tanh_(gn0 + bi0 + rA * (v0[2] + bh0));
    float h0 = (1.0f - zA) * nA + zA * hprev0;
    float rB = sigm(gr1 + v1[0] + br1);
    float zB = sigm(gz1 + v1[1] + bz1);
    float nB = tanh_(gn1 + bi1 + rB * (v1[2] + bh1));
    float h1 = (1.0f - zB) * nB + zB * hprev1;
    hprev0 = h0; hprev1 = h1;

    if (ys_out){
      float2 yv = { h0, h1 };
      *(float2*)&ys_out[((size_t)t * BATCH + growL) * HID + colc0] = yv;
    }
    if (x_next){
      ushort2 xv = { f2bf(h0), f2bf(h1) };
      *(ushort2*)&x_next[((size_t)s * BATCH + growL) * HID + colc0] = xv;
    }
    if (t == SEQ-1){
      float2 sv = { h0, h1 };
      *(float2*)&state_out[(size_t)growL * HID + colc0] = sv;
    }
    if (s == TCH-1){
      float2 hv2 = { h0, h1 };
      *(float2*)&hf32[(size_t)growL * HID + colc0] = hv2;
    }

    ushort2 hb2 = { f2bf(h0), f2bf(h1) };
    *(ushort2*)&hvt[crow][ccol] = hb2;
    __syncthreads();

    if (tid < 128){
      int row = tid >> 2, c4 = (tid & 3) * 4;
      unsigned long long u = *(const unsigned long long*)&hvt[row][c4];
      __hip_atomic_store(hout + (((size_t)(rowbase + row) * HID + c0 + c4) >> 2), u,
                         __ATOMIC_RELAXED, __HIP_MEMORY_SCOPE_AGENT);
    }
    __syncthreads();   // drains each wave's vmcnt before barrier -> stores at LLC

    if (tid == 0 && s < TCH-1)
      __hip_atomic_fetch_add(cnt + rg * TCH + s, 1u,
                             __ATOMIC_RELAXED, __HIP_MEMORY_SCOPE_AGENT);
  }
}

// ---------------- launch ----------------

extern "C" void kernel_launch(void* const* d_in, const int* in_sizes, int n_in,
                              void* d_out, int out_size, void* d_ws, size_t ws_size,
                              hipStream_t stream){
  (void)in_sizes; (void)n_in; (void)out_size; (void)ws_size;
  const int*   src  = (const int*)  d_in[0];
  const float* embW = (const float*)d_in[1];
  const float* Wih  = (const float*)d_in[2];
  const float* Whh  = (const float*)d_in[3];
  const float* bih  = (const float*)d_in[4];
  const float* bhh  = (const float*)d_in[5];
  float* out = (float*)d_out;

  char* ws = (char*)d_ws;
  size_t off = 0;
  auto carve = [&](size_t bytes) -> void* {
    void* p = ws + off;
    off += (bytes + 255) & ~(size_t)255;
    return p;
  };
  const size_t WELEM = (size_t)2 * H3 * HID;
  unsigned short* wihb = (unsigned short*)carve(WELEM * 2);
  unsigned short* whhb = (unsigned short*)carve(WELEM * 2);
  unsigned short* x0   = (unsigned short*)carve((size_t)SEQ*BATCH*HID*2);
  unsigned short* x1   = (unsigned short*)carve((size_t)SEQ*BATCH*HID*2);
  float*          gi   = (float*)         carve((size_t)CROWS*H3*4);
  unsigned long long* hbA = (unsigned long long*)carve((size_t)BATCH*HID*2);
  unsigned long long* hbB = (unsigned long long*)carve((size_t)BATCH*HID*2);
  float*          hf32 = (float*)         carve((size_t)BATCH*HID*4);
  unsigned*       cnt  = (unsigned*)      carve((size_t)16 * 4 * TCH * 4);

  cvt_bf16<<<2048, 256, 0, stream>>>(Wih, wihb, (int)(WELEM/4));
  cvt_bf16<<<2048, 256, 0, stream>>>(Whh, whhb, (int)(WELEM/4));
  embed_gather<<<SEQ*BATCH, 256, 0, stream>>>(src, embW, x0);
  zero_u32<<<8, 256, 0, stream>>>(cnt, 16 * 4 * TCH);

  float* state = out + (size_t)SEQ*BATCH*HID;
  for (int l = 0; l < 2; ++l){
    const float* bihl = bih + l*H3;
    const float* bhhl = bhh + l*H3;
    const unsigned short* wl = wihb + (size_t)l*H3*HID;
    const unsigned short* vl = whhb + (size_t)l*H3*HID;
    for (int cch = 0; cch < NCH; ++cch){
      const unsigned short* Achunk = (l == 0) ? (x0 + (size_t)cch*CROWS*HID)
                                              : (x1 + (size_t)cch*CROWS*HID);
      gemm_xw<<<dim3(CROWS/BM, H3/BN), 256, 0, stream>>>(Achunk, wl, gi);
      int launch_id = l*NCH + cch;
      gru_persist<<<256, 256, 0, stream>>>(
          vl, bihl, bhhl, gi,
          (l == 1) ? out : nullptr,
          (l == 0) ? (x1 + (size_t)cch*CROWS*HID) : nullptr,
          hbA, hbB, hf32,
          state + (size_t)l*BATCH*HID,
          cch*TCH,
          cnt + (size_t)launch_id * 4 * TCH);
    }
  }
}